// Round 9
// baseline (164.272 us; speedup 1.0000x reference)
//
#include <hip/hip_runtime.h>
#include <math.h>

#define Bb 32
#define Nn 1024
#define Mm 64
#define Rr 4
#define Hh 512
#define NINq 256
#define Pp 471
#define EPSN 1e-8f

__device__ __forceinline__ float sigm(float x){ return 1.0f/(1.0f+expf(-x)); }

// ---------------- gates GEMM: direct-gather A, 16 K-chunk partials ----------------
__global__ __launch_bounds__(256) void k_gates(
    const float* __restrict__ X, const float* __restrict__ pr,
    const float* __restrict__ h0, const float* __restrict__ Wx,
    const float* __restrict__ Wh, float* __restrict__ gpart)
{
  __shared__ float lin[32][64];
  int tid = threadIdx.x;
  int col = blockIdx.x*64 + (tid & 63);
  int bg  = tid >> 6;
  int k0  = blockIdx.y*64;
#pragma unroll
  for (int q=0;q<8;q++){
    int idx = tid + 256*q;
    int bb = idx >> 6, kk = idx & 63;
    int k = k0 + kk;
    float v;
    if (k < 256)      v = X [bb*NINq + k];
    else if (k < 512) v = pr[bb*(Rr*Mm) + (k-256)];
    else              v = h0[bb*Hh + (k-512)];
    lin[bb][kk] = v;
  }
  __syncthreads();
  const float* Wr = (k0 < 512) ? (Wx + (size_t)k0*2048)
                               : (Wh + (size_t)(k0-512)*2048);
  float acc[8];
#pragma unroll
  for (int i=0;i<8;i++) acc[i]=0.f;
#pragma unroll 8
  for (int kk=0; kk<64; ++kk){
    float wv = Wr[(size_t)kk*2048 + col];
#pragma unroll
    for (int bb=0; bb<8; ++bb) acc[bb] += wv * lin[bg*8+bb][kk];
  }
  float* gp = gpart + (size_t)blockIdx.y*65536;
#pragma unroll
  for (int bb=0; bb<8; ++bb)
    gp[(bg*8+bb)*2048 + col] = acc[bb];
}

// ---------------- LSTM epilogue: sum 16 gate partials + bias; scatter h/emb ----------------
__global__ void k_lstm_ep(const float* __restrict__ gpart, const float* __restrict__ lb,
                          const float* __restrict__ c0, const float* __restrict__ emb,
                          float* __restrict__ hcat, float* __restrict__ ocat)
{
  int idx = blockIdx.x*blockDim.x + threadIdx.x;
  if (idx >= Bb*Hh) return;
  int b = idx >> 9, j = idx & 511;
  float gi = lb[j], gf = lb[j+512], gg = lb[j+1024], go = lb[j+1536];
  for (int c=0;c<16;++c){
    const float* gp = gpart + (size_t)c*65536 + b*2048;
    gi += gp[j]; gf += gp[j+512]; gg += gp[j+1024]; go += gp[j+1536];
  }
  float c = sigm(gf)*c0[idx] + sigm(gi)*tanhf(gg);
  float h = sigm(go)*tanhf(c);
  float e = emb[idx];
  hcat[b*1024 + j]       = h;
  hcat[b*1024 + 512 + j] = e;
  ocat[b*1280 + j]       = h;
  ocat[b*1280 + 512 + j] = e;
}

// ---------------- para GEMM: A=hcat, 16 K-chunk partials ----------------
__global__ __launch_bounds__(256) void k_para(
    const float* __restrict__ hcat, const float* __restrict__ Wp,
    float* __restrict__ ppart)
{
  __shared__ float lin[32][64];
  int tid = threadIdx.x;
  int col = blockIdx.x*64 + (tid & 63);
  int bg  = tid >> 6;
  int k0  = blockIdx.y*64;
#pragma unroll
  for (int q=0;q<8;q++){
    int idx = tid + 256*q;
    int bb = idx >> 6, kk = idx & 63;
    lin[bb][kk] = hcat[bb*1024 + k0 + kk];
  }
  __syncthreads();
  int colc = (col < Pp) ? col : (Pp-1);
  const float* Wr = Wp + (size_t)k0*Pp;
  float acc[8];
#pragma unroll
  for (int i=0;i<8;i++) acc[i]=0.f;
#pragma unroll 8
  for (int kk=0; kk<64; ++kk){
    float wv = Wr[(size_t)kk*Pp + colc];
#pragma unroll
    for (int bb=0; bb<8; ++bb) acc[bb] += wv * lin[bg*8+bb][kk];
  }
  if (col < Pp) {
    float* pp = ppart + (size_t)blockIdx.y*16384;
#pragma unroll
    for (int bb=0; bb<8; ++bb)
      pp[(bg*8+bb)*512 + col] = acc[bb];
  }
}

// ---------------- fused: ppart-sum + LN + alloc(bitonic, LDS-only) + write-sim + ww + Sp/Sw ----------------
__global__ __launch_bounds__(1024) void k_waddr(
    const float* __restrict__ ppart, const float* __restrict__ bp,
    const float* __restrict__ ln_g, const float* __restrict__ ln_b,
    const float* __restrict__ rwp, const float* __restrict__ wwp,
    const float* __restrict__ up, const float* __restrict__ mem,
    const float* __restrict__ prec,
    float* __restrict__ pvec, float* __restrict__ wwb, float* __restrict__ spsw)
{
  __shared__ float red[16];
  __shared__ float pvs[512];
  __shared__ float fg[4];
  __shared__ float kdir[64];
  __shared__ float scal[4];
  __shared__ unsigned long long sk[1024];
  __shared__ float wsums[16];
  __shared__ float af[1024];
  __shared__ float red8[16][8];
  int b = blockIdx.x, tid = threadIdx.x;
  int lane = tid & 63, wv = tid >> 6;
  // ---- LN ----
  float acc = 0.f, d = 0.f;
  if (tid < 512) {
    if (tid < Pp) {
      acc = bp[tid];
#pragma unroll
      for (int c=0;c<16;++c) acc += ppart[(size_t)c*16384 + b*512 + tid];
    }
    float s = acc;
    for (int o=32;o;o>>=1) s += __shfl_xor(s,o,64);
    if (lane==0) red[wv] = s;
  }
  __syncthreads();
  if (tid < 8){ float xx = red[tid]; for (int o=4;o;o>>=1) xx += __shfl_xor(xx,o,64); if (!tid) red[0]=xx; }
  __syncthreads();
  float mu = red[0] / (float)Pp;
  __syncthreads();
  if (tid < 512) {
    d = (tid < Pp) ? (acc - mu) : 0.f;
    float s2 = d*d;
    for (int o=32;o;o>>=1) s2 += __shfl_xor(s2,o,64);
    if (lane==0) red[wv] = s2;
  }
  __syncthreads();
  if (tid < 8){ float xx = red[tid]; for (int o=4;o;o>>=1) xx += __shfl_xor(xx,o,64); if (!tid) red[0]=xx; }
  __syncthreads();
  float var = red[0] / (float)Pp;
  if (tid < Pp) {
    float y = d / sqrtf(var + 1e-5f) * ln_g[tid] + ln_b[tid];
    pvec[b*512 + tid] = y;
    pvs[tid] = y;
  }
  __syncthreads();
  // ---- scalars from pvs ----
  if (tid < 4) fg[tid] = sigm(pvs[128+tid]);
  if (wv == 0) {
    float v = pvs[146 + lane];
    float s = v*v;
    for (int o=32;o;o>>=1) s += __shfl_xor(s,o,64);
    kdir[lane] = v / (sqrtf(s) + EPSN);
  }
  if (tid == 0) {
    scal[0] = sigm(pvs[132]);               // alloc gate
    scal[1] = sigm(pvs[133]);               // write gate
    scal[2] = 1.f + log1pf(expf(pvs[210])); // write strength
  }
  __syncthreads();
  // ---- usage + bitonic argsort + cumprod -> af (LDS only) ----
  float psi = 1.f;
#pragma unroll
  for (int r=0;r<4;r++) psi *= 1.f - fg[r]*rwp[b*(Rr*Nn) + r*Nn + tid];
  float u = up[b*Nn+tid], w = wwp[b*Nn+tid];
  float usage = (u + w - u*w)*psi;
  unsigned long long key = ((unsigned long long)__float_as_uint(usage) << 32) | (unsigned)tid;
  for (int k=2; k<=1024; k<<=1) {
    for (int j=k>>1; j>0; j>>=1) {
      bool lower = (tid & j) == 0;
      bool asc   = (tid & k) == 0;
      unsigned long long pk;
      if (j >= 64) {
        sk[tid] = key; __syncthreads();
        pk = sk[tid ^ j];
        __syncthreads();
      } else {
        pk = __shfl_xor(key, j, 64);
      }
      key = ((key < pk) == (lower == asc)) ? key : pk;
    }
  }
  float us = __uint_as_float((unsigned)(key >> 32));
  int order = (int)(key & 1023u);
  float v = us;
#pragma unroll
  for (int dd=1; dd<64; dd<<=1) {
    float p = __shfl_up(v, dd, 64);
    if (lane >= dd) v *= p;
  }
  if (lane == 63) wsums[wv] = v;
  __syncthreads();
  if (wv == 0) {
    float t = (lane < 16) ? wsums[lane] : 1.f;
#pragma unroll
    for (int dd=1; dd<16; dd<<=1) {
      float p = __shfl_up(t, dd, 64);
      if (lane >= dd) t *= p;
    }
    if (lane < 16) wsums[lane] = t;
  }
  __syncthreads();
  float prefix = (wv > 0) ? wsums[wv-1] : 1.f;
  af[order] = (1.f - us) * (v * prefix);
  // ---- write-key sim: thread = memory row ----
  float beta = scal[2];
  float dot = 0.f, s2 = 0.f;
  const float* mrow = mem + (size_t)(b*Nn + tid)*Mm;
#pragma unroll
  for (int j=0;j<16;j++){
    float4 mv = *reinterpret_cast<const float4*>(&mrow[j*4]);
    dot += mv.x*kdir[j*4] + mv.y*kdir[j*4+1] + mv.z*kdir[j*4+2] + mv.w*kdir[j*4+3];
    s2  += mv.x*mv.x + mv.y*mv.y + mv.z*mv.z + mv.w*mv.w;
  }
  float sim = beta * dot / (sqrtf(s2) + EPSN);
  // ---- block softmax over sim ----
  float m_ = sim;
  for (int o=32;o;o>>=1) m_ = fmaxf(m_, __shfl_xor(m_,o,64));
  if (lane==0) red[wv] = m_;
  __syncthreads();
  if (tid < 16){ float x = red[tid]; for (int o=8;o;o>>=1) x = fmaxf(x,__shfl_xor(x,o,64)); if (!tid) red[0]=x; }
  __syncthreads();
  float gmax = red[0];
  __syncthreads();
  float e = expf(sim - gmax);
  float ss = e;
  for (int o=32;o;o>>=1) ss += __shfl_xor(ss,o,64);
  if (lane==0) red[wv] = ss;
  __syncthreads();
  if (tid < 16){ float x = red[tid]; for (int o=8;o;o>>=1) x += __shfl_xor(x,o,64); if (!tid) red[0]=x; }
  __syncthreads();
  float wcn = e / red[0];
  float ag = scal[0], wg = scal[1];
  float wwn = wg * (ag*af[tid] + (1.f-ag)*wcn);
  wwb[b*Nn + tid] = wwn;
  // ---- Sp/Sw ----
  float p = prec[b*Nn + tid];
#pragma unroll
  for (int r=0;r<4;r++){
    float a = rwp[b*(Rr*Nn) + r*Nn + tid];
    float x1 = p*a, x2 = wwn*a;
    for (int o=32;o;o>>=1){ x1 += __shfl_xor(x1,o,64); x2 += __shfl_xor(x2,o,64); }
    if (lane==0){ red8[wv][r] = x1; red8[wv][4+r] = x2; }
  }
  __syncthreads();
  if (tid < 8) {
    float s = 0.f;
    for (int w2=0; w2<16; ++w2) s += red8[w2][tid];
    spsw[b*8 + tid] = s;
  }
}

// ---------------- fused: link scan 128-row tiles (x<16) + memupd (x>=16) ----------------
// links role: sg = x>>1 owns rows sg*128..+127; half = x&1 owns cols half*512..+511.
// T partials indexed by sg (8); S partials by half (2). Shared-mem overlaid manually.
__global__ __launch_bounds__(256) void k_linksmem(
    const float* __restrict__ links, const float* __restrict__ rwp,
    const float* __restrict__ wwb, const float* __restrict__ pvec,
    const float* __restrict__ mem,
    float* __restrict__ S1p, float* __restrict__ S2p,
    float* __restrict__ T1p, float* __restrict__ T2p,
    float* __restrict__ diag, float* __restrict__ memn, float* __restrict__ simr)
{
  __shared__ float sm[9856];   // links: tile[128][65]|ai|wai|aj|waj ; memupd overlays front
  int b = blockIdx.y;
  int tid = threadIdx.x;
  if (blockIdx.x >= 16) {
    // ---- memupd role ----
    float* ev    = sm;          // 64
    float* wvv   = sm + 64;     // 64
    float* kdir4 = sm + 128;    // [4][64]
    float* beta4 = sm + 384;    // 4
    int stripe = blockIdx.x - 16;
    int wv = tid>>6, lane = tid&63;
    const float* pv = pvec + b*512;
    {
      float kv = pv[211 + wv*64 + lane];
      float s = kv*kv;
      for (int o=32;o;o>>=1) s += __shfl_xor(s,o,64);
      kdir4[wv*64+lane] = kv/(sqrtf(s)+EPSN);
      if (lane==0) beta4[wv] = 1.f + log1pf(expf(pv[467+wv]));
    }
    if (tid < 64) { wvv[tid] = pv[tid]; ev[tid] = sigm(pv[64+tid]); }
    __syncthreads();
    for (int t=0;t<16;++t){
      int n = stripe*64 + wv*16 + t;
      float wwn = wwb[b*Nn + n];
      float v = mem[(b*Nn+n)*Mm + lane];
      float nv = v*(1.f - wwn*ev[lane]) + wwn*wvv[lane];
      memn[(b*Nn+n)*Mm + lane] = nv;
      float s2 = nv*nv;
      float d0 = nv*kdir4[0*64+lane], d1 = nv*kdir4[1*64+lane];
      float d2 = nv*kdir4[2*64+lane], d3 = nv*kdir4[3*64+lane];
      for (int o=32;o;o>>=1){
        s2 += __shfl_xor(s2,o,64);
        d0 += __shfl_xor(d0,o,64); d1 += __shfl_xor(d1,o,64);
        d2 += __shfl_xor(d2,o,64); d3 += __shfl_xor(d3,o,64);
      }
      if (lane==0){
        float inv = 1.f/(sqrtf(s2)+EPSN);
        simr[(b*4+0)*Nn+n] = beta4[0]*d0*inv;
        simr[(b*4+1)*Nn+n] = beta4[1]*d1*inv;
        simr[(b*4+2)*Nn+n] = beta4[2]*d2*inv;
        simr[(b*4+3)*Nn+n] = beta4[3]*d3*inv;
      }
    }
    return;
  }
  // ---- links role ----
  float (*tile)[65] = (float(*)[65])sm;   // 128 x 65
  float* ai  = sm + 8320;                 // [4][128]
  float* wai = sm + 8832;                 // [4][128]
  float* aj  = sm + 9344;                 // [4][64]
  float* waj = sm + 9600;                 // [4][64]
  int sg = blockIdx.x >> 1, half = blockIdx.x & 1;
  int i0 = sg*128, jbase = half*512;
#pragma unroll
  for (int e=0;e<2;++e){
    int idx = tid + 256*e;
    int r = idx>>7, ii = idx&127;
    float a = rwp[b*(Rr*Nn) + r*Nn + i0+ii];
    ai[r*128+ii]  = a;
    wai[r*128+ii] = a * wwb[b*Nn + i0+ii];
  }
  float s1a[2][4] = {{0,0,0,0},{0,0,0,0}}, s2a[2][4] = {{0,0,0,0},{0,0,0,0}};
  const float* Lb = links + (size_t)b*Nn*Nn;
  const int lrow = tid>>4, c4 = tid&15;   // rows lrow+16q, cols c4*4..+3
  float4 pv4[8];
#pragma unroll
  for (int q=0;q<8;q++)
    pv4[q] = *reinterpret_cast<const float4*>(&Lb[(size_t)(i0+lrow+16*q)*Nn + jbase + c4*4]);
  for (int t=0; t<8; ++t) {
    int j0 = jbase + t*64;
    __syncthreads();
#pragma unroll
    for (int q=0;q<8;q++){
      int row = lrow + 16*q;
      float4 v = pv4[q];
      tile[row][c4*4+0]=v.x; tile[row][c4*4+1]=v.y;
      tile[row][c4*4+2]=v.z; tile[row][c4*4+3]=v.w;
    }
    {
      int r = tid>>6, jj = tid&63;
      float a = rwp[b*(Rr*Nn) + r*Nn + j0+jj];
      aj[r*64+jj]  = a;
      waj[r*64+jj] = a * wwb[b*Nn + j0+jj];
    }
    __syncthreads();
    if (t < 7) {
      int j0n = j0 + 64;
#pragma unroll
      for (int q=0;q<8;q++)
        pv4[q] = *reinterpret_cast<const float4*>(&Lb[(size_t)(i0+lrow+16*q)*Nn + j0n + c4*4]);
    }
    // diag: rowblock = half*8+t belongs to this block iff rowblock>>1 == sg
    int rowblock = half*8 + t;
    if ((rowblock>>1) == sg && tid < 64) {
      int lr0 = (rowblock&1)*64;
      diag[b*Nn + rowblock*64 + tid] = tile[lr0+tid][tid];
    }
    // phase A: row partials for 128 rows (two 64-row halves)
#pragma unroll
    for (int h=0;h<2;++h){
      int ii = h*64 + (tid>>2);
      int c = tid&3;
      float p1[4]={0,0,0,0}, p2[4]={0,0,0,0};
      for (int k=0;k<16;k++){
        int jj = c*16+k;
        float v = tile[ii][jj];
#pragma unroll
        for (int r=0;r<4;r++){ p1[r] += v*aj[r*64+jj]; p2[r] += v*waj[r*64+jj]; }
      }
#pragma unroll
      for (int r=0;r<4;r++){
        p1[r] += __shfl_xor(p1[r],1,64); p1[r] += __shfl_xor(p1[r],2,64);
        p2[r] += __shfl_xor(p2[r],1,64); p2[r] += __shfl_xor(p2[r],2,64);
      }
      if (c==0){
#pragma unroll
        for (int r=0;r<4;r++){ s1a[h][r] += p1[r]; s2a[h][r] += p2[r]; }
      }
    }
    // phase B: col partials over 128 rows
    {
      int jj = tid>>2, q = tid&3;
      float p1[4]={0,0,0,0}, p2[4]={0,0,0,0};
      for (int k=0;k<32;k++){
        int ii = q*32+k;
        float v = tile[ii][jj];
#pragma unroll
        for (int r=0;r<4;r++){ p1[r] += v*ai[r*128+ii]; p2[r] += v*wai[r*128+ii]; }
      }
#pragma unroll
      for (int r=0;r<4;r++){
        p1[r] += __shfl_xor(p1[r],1,64); p1[r] += __shfl_xor(p1[r],2,64);
        p2[r] += __shfl_xor(p2[r],1,64); p2[r] += __shfl_xor(p2[r],2,64);
      }
      if (q==0){
#pragma unroll
        for (int r=0;r<4;r++){
          size_t o = (size_t)((b*4+r)*8 + sg)*Nn + j0 + jj;
          T1p[o] = p1[r];
          T2p[o] = p2[r];
        }
      }
    }
  }
  if ((tid&3)==0){
    int ii = tid>>2;
#pragma unroll
    for (int h=0;h<2;++h){
#pragma unroll
      for (int r=0;r<4;r++){
        size_t o = (size_t)(((half*Bb + b)*4 + r))*Nn + i0 + h*64 + ii;
        S1p[o] = s1a[h][r];
        S2p[o] = s2a[h][r];
      }
    }
  }
}

// ---------------- fused: 4-way-parallel softmax+combine + reads GEMV + out bias ----------------
__global__ __launch_bounds__(1024) void k_rread(
    const float* __restrict__ pvec, const float* __restrict__ rwp,
    const float* __restrict__ prec, const float* __restrict__ wwb,
    const float* __restrict__ T1p, const float* __restrict__ T2p,
    const float* __restrict__ S1p, const float* __restrict__ S2p,
    const float* __restrict__ spsw, const float* __restrict__ diag,
    const float* __restrict__ simr, const float* __restrict__ memn,
    const float* __restrict__ bo, float* __restrict__ ocat, float* __restrict__ out)
{
  __shared__ float rwl[4][1024];
  __shared__ float redm[4][4], reds[4][4];
  __shared__ float rm3s[4][3];
  __shared__ float rp[16][4][64];
  int b = blockIdx.x, tid = threadIdx.x;
  int g = tid>>8, t256 = tid&255;           // group g handles r = g
  int wv4 = (tid>>6)&3, lane = tid&63;
  const float* pv = pvec + b*512;
  if (tid < 4) {
    float x0 = pv[134+tid*3], x1 = pv[134+tid*3+1], x2 = pv[134+tid*3+2];
    float mx = fmaxf(x0, fmaxf(x1,x2));
    float e0 = expf(x0-mx), e1 = expf(x1-mx), e2 = expf(x2-mx);
    float s = e0+e1+e2;
    rm3s[tid][0]=e0/s; rm3s[tid][1]=e1/s; rm3s[tid][2]=e2/s;
  }
  // load 4 n's per thread: n = t256 + 256*q
  float v[4];
#pragma unroll
  for (int q=0;q<4;q++) v[q] = simr[(b*4+g)*Nn + t256 + 256*q];
  float m_ = fmaxf(fmaxf(v[0],v[1]), fmaxf(v[2],v[3]));
  for (int o=32;o;o>>=1) m_ = fmaxf(m_, __shfl_xor(m_,o,64));
  if (lane==0) redm[g][wv4] = m_;
  __syncthreads();
  float gmax = fmaxf(fmaxf(redm[g][0],redm[g][1]), fmaxf(redm[g][2],redm[g][3]));
  float e[4];
  float ss = 0.f;
#pragma unroll
  for (int q=0;q<4;q++){ e[q] = expf(v[q]-gmax); ss += e[q]; }
  for (int o=32;o;o>>=1) ss += __shfl_xor(ss,o,64);
  if (lane==0) reds[g][wv4] = ss;
  __syncthreads();
  float tot = reds[g][0]+reds[g][1]+reds[g][2]+reds[g][3];
  float Spr = spsw[b*8+g], Swr = spsw[b*8+4+g];
#pragma unroll
  for (int q=0;q<4;q++){
    int n = t256 + 256*q;
    float rc = e[q]/tot;
    float w_n = wwb[b*Nn + n];
    float p_n = prec[b*Nn + n];
    float Lii = diag[b*Nn + n];
    float a = rwp[b*(Rr*Nn)+g*Nn+n];
    float s1v = S1p[(size_t)((0*Bb+b)*4+g)*Nn + n] + S1p[(size_t)((1*Bb+b)*4+g)*Nn + n];
    float s2v = S2p[(size_t)((0*Bb+b)*4+g)*Nn + n] + S2p[(size_t)((1*Bb+b)*4+g)*Nn + n];
    float t1v = 0.f, t2v = 0.f;
#pragma unroll
    for (int st=0; st<8; ++st){
      size_t o = (size_t)((b*4+g)*8 + st)*Nn + n;
      t1v += T1p[o];
      t2v += T2p[o];
    }
    float fwd = (1.f-w_n)*(s1v - Lii*a) - (s2v - Lii*w_n*a) + w_n*(Spr - p_n*a);
    float bwd = (1.f-w_n)*(t1v - Lii*a) - (t2v - w_n*Lii*a) + p_n*(Swr - w_n*a);
    rwl[g][n] = rm3s[g][1]*rc + rm3s[g][0]*bwd + rm3s[g][2]*fwd;
  }
  __syncthreads();
  // reads = rw @ memn : wave wv covers n in [wv*64, wv*64+64)
  int wv = tid>>6;
  float a0=0.f, a1=0.f, a2=0.f, a3=0.f;
  for (int t=0;t<64;++t){
    int n = wv*64 + t;
    float mv = memn[(size_t)(b*Nn+n)*Mm + lane];
    a0 += rwl[0][n]*mv; a1 += rwl[1][n]*mv; a2 += rwl[2][n]*mv; a3 += rwl[3][n]*mv;
  }
  rp[wv][0][lane]=a0; rp[wv][1][lane]=a1; rp[wv][2][lane]=a2; rp[wv][3][lane]=a3;
  __syncthreads();
  if (tid < 256) {
    int r = tid>>6, m = tid&63;
    float s = 0.f;
#pragma unroll
    for (int w2=0;w2<16;++w2) s += rp[w2][r][m];
    ocat[b*1280 + 1024 + r*64 + m] = s;
    out[b*256 + tid] = bo[tid];
  }
}

// ---------------- output GEMM (atomic; out bias-inited by k_rread) ----------------
__global__ __launch_bounds__(256) void k_gout(
    const float* __restrict__ ocat, const float* __restrict__ Wo,
    float* __restrict__ out)
{
  __shared__ float lin[32][64];
  int tid = threadIdx.x;
  int col = blockIdx.x*64 + (tid & 63);
  int bg  = tid >> 6;
  int k0  = blockIdx.y*64;
#pragma unroll
  for (int q=0;q<8;q++){
    int idx = tid + 256*q;
    int bb = idx >> 6, kk = idx & 63;
    lin[bb][kk] = ocat[bb*1280 + k0 + kk];
  }
  __syncthreads();
  const float* Wr = Wo + (size_t)k0*256;
  float acc[8];
#pragma unroll
  for (int i=0;i<8;i++) acc[i]=0.f;
#pragma unroll 8
  for (int kk=0; kk<64; ++kk){
    float wv = Wr[(size_t)kk*256 + col];
#pragma unroll
    for (int bb=0; bb<8; ++bb) acc[bb] += wv * lin[bg*8+bb][kk];
  }
#pragma unroll
  for (int bb=0; bb<8; ++bb)
    atomicAdd(&out[(size_t)(bg*8+bb)*256 + col], acc[bb]);
}

extern "C" void kernel_launch(void* const* d_in, const int* in_sizes, int n_in,
                              void* d_out, int out_size, void* d_ws, size_t ws_size,
                              hipStream_t stream)
{
  (void)in_sizes; (void)n_in; (void)out_size; (void)ws_size;
  const float* X    = (const float*)d_in[0];
  const float* emb  = (const float*)d_in[1];
  const float* mem  = (const float*)d_in[2];
  const float* prvr = (const float*)d_in[3];
  const float* h0   = (const float*)d_in[4];
  const float* c0   = (const float*)d_in[5];
  const float* rwp  = (const float*)d_in[6];
  const float* wwp  = (const float*)d_in[7];
  const float* up   = (const float*)d_in[8];
  const float* prec = (const float*)d_in[9];
  const float* links= (const float*)d_in[10];
  const float* Wx   = (const float*)d_in[11];
  const float* Wh   = (const float*)d_in[12];
  const float* lb   = (const float*)d_in[13];
  const float* Wp   = (const float*)d_in[14];
  const float* bp   = (const float*)d_in[15];
  const float* lng  = (const float*)d_in[16];
  const float* lnb  = (const float*)d_in[17];
  const float* Wo   = (const float*)d_in[18];
  const float* bo   = (const float*)d_in[19];
  float* out = (float*)d_out;
  float* ws  = (float*)d_ws;

  float* memn  = ws;                       // 2097152
  float* T1p   = memn  + 2097152;          // 1048576 (32b x 4r x 8sg x 1024)
  float* T2p   = T1p   + 1048576;          // 1048576
  float* S1p   = T2p   + 1048576;          // 262144  (2half x 32b x 4r x 1024)
  float* S2p   = S1p   + 262144;           // 262144
  float* gpart = S2p   + 262144;           // 1048576 (16c x 32b x 2048)
  float* ppart = gpart + 1048576;          // 262144  (16c x 32b x 512)
  float* pvec  = ppart + 262144;           // 16384   (stride 512, 471 used)
  float* wwb   = pvec  + 16384;            // 32768
  float* ocat  = wwb   + 32768;            // 40960   [h|emb|reads]
  float* spsw  = ocat  + 40960;            // 256
  float* simr  = spsw  + 256;              // 131072
  float* diag  = simr  + 131072;           // 32768
  float* hcat  = diag  + 32768;            // 32768   [h|emb]

  k_gates   <<<dim3(32,16), dim3(256),  0, stream>>>(X, prvr, h0, Wx, Wh, gpart);
  k_lstm_ep <<<dim3(64),    dim3(256),  0, stream>>>(gpart, lb, c0, emb, hcat, ocat);
  k_para    <<<dim3(8,16),  dim3(256),  0, stream>>>(hcat, Wp, ppart);
  k_waddr   <<<dim3(32),    dim3(1024), 0, stream>>>(ppart, bp, lng, lnb, rwp, wwp, up,
                                                     mem, prec, pvec, wwb, spsw);
  k_linksmem<<<dim3(32,32), dim3(256),  0, stream>>>(links, rwp, wwb, pvec, mem,
                                                     S1p, S2p, T1p, T2p, diag, memn, simr);
  k_rread   <<<dim3(32),    dim3(1024), 0, stream>>>(pvec, rwp, prec, wwb, T1p, T2p,
                                                     S1p, S2p, spsw, diag, simr, memn,
                                                     bo, ocat, out);
  k_gout    <<<dim3(4,20),  dim3(256),  0, stream>>>(ocat, Wo, out);
}

// Round 10
// 130.356 us; speedup vs baseline: 1.2602x; 1.2602x over previous
//
#include <hip/hip_runtime.h>
#include <math.h>

#define Bb 32
#define Nn 1024
#define Mm 64
#define Rr 4
#define Hh 512
#define NINq 256
#define Pp 471
#define EPSN 1e-8f

__device__ __forceinline__ float sigm(float x){ return 1.0f/(1.0f+expf(-x)); }

// ---------------- gates GEMM: direct-gather A, 16 K-chunk partials ----------------
__global__ __launch_bounds__(256) void k_gates(
    const float* __restrict__ X, const float* __restrict__ pr,
    const float* __restrict__ h0, const float* __restrict__ Wx,
    const float* __restrict__ Wh, float* __restrict__ gpart)
{
  __shared__ float lin[32][64];
  int tid = threadIdx.x;
  int col = blockIdx.x*64 + (tid & 63);
  int bg  = tid >> 6;
  int k0  = blockIdx.y*64;
#pragma unroll
  for (int q=0;q<8;q++){
    int idx = tid + 256*q;
    int bb = idx >> 6, kk = idx & 63;
    int k = k0 + kk;
    float v;
    if (k < 256)      v = X [bb*NINq + k];
    else if (k < 512) v = pr[bb*(Rr*Mm) + (k-256)];
    else              v = h0[bb*Hh + (k-512)];
    lin[bb][kk] = v;
  }
  __syncthreads();
  const float* Wr = (k0 < 512) ? (Wx + (size_t)k0*2048)
                               : (Wh + (size_t)(k0-512)*2048);
  float acc[8];
#pragma unroll
  for (int i=0;i<8;i++) acc[i]=0.f;
#pragma unroll 8
  for (int kk=0; kk<64; ++kk){
    float wv = Wr[(size_t)kk*2048 + col];
#pragma unroll
    for (int bb=0; bb<8; ++bb) acc[bb] += wv * lin[bg*8+bb][kk];
  }
  float* gp = gpart + (size_t)blockIdx.y*65536;
#pragma unroll
  for (int bb=0; bb<8; ++bb)
    gp[(bg*8+bb)*2048 + col] = acc[bb];
}

// ---------------- LSTM epilogue: sum 16 gate partials + bias; scatter h/emb ----------------
__global__ void k_lstm_ep(const float* __restrict__ gpart, const float* __restrict__ lb,
                          const float* __restrict__ c0, const float* __restrict__ emb,
                          float* __restrict__ hcat, float* __restrict__ ocat)
{
  int idx = blockIdx.x*blockDim.x + threadIdx.x;
  if (idx >= Bb*Hh) return;
  int b = idx >> 9, j = idx & 511;
  float gi = lb[j], gf = lb[j+512], gg = lb[j+1024], go = lb[j+1536];
  for (int c=0;c<16;++c){
    const float* gp = gpart + (size_t)c*65536 + b*2048;
    gi += gp[j]; gf += gp[j+512]; gg += gp[j+1024]; go += gp[j+1536];
  }
  float c = sigm(gf)*c0[idx] + sigm(gi)*tanhf(gg);
  float h = sigm(go)*tanhf(c);
  float e = emb[idx];
  hcat[b*1024 + j]       = h;
  hcat[b*1024 + 512 + j] = e;
  ocat[b*1280 + j]       = h;
  ocat[b*1280 + 512 + j] = e;
}

// ---------------- para GEMM: A=hcat, 16 K-chunk partials ----------------
__global__ __launch_bounds__(256) void k_para(
    const float* __restrict__ hcat, const float* __restrict__ Wp,
    float* __restrict__ ppart)
{
  __shared__ float lin[32][64];
  int tid = threadIdx.x;
  int col = blockIdx.x*64 + (tid & 63);
  int bg  = tid >> 6;
  int k0  = blockIdx.y*64;
#pragma unroll
  for (int q=0;q<8;q++){
    int idx = tid + 256*q;
    int bb = idx >> 6, kk = idx & 63;
    lin[bb][kk] = hcat[bb*1024 + k0 + kk];
  }
  __syncthreads();
  int colc = (col < Pp) ? col : (Pp-1);
  const float* Wr = Wp + (size_t)k0*Pp;
  float acc[8];
#pragma unroll
  for (int i=0;i<8;i++) acc[i]=0.f;
#pragma unroll 8
  for (int kk=0; kk<64; ++kk){
    float wv = Wr[(size_t)kk*Pp + colc];
#pragma unroll
    for (int bb=0; bb<8; ++bb) acc[bb] += wv * lin[bg*8+bb][kk];
  }
  if (col < Pp) {
    float* pp = ppart + (size_t)blockIdx.y*16384;
#pragma unroll
    for (int bb=0; bb<8; ++bb)
      pp[(bg*8+bb)*512 + col] = acc[bb];
  }
}

// ---------------- fused: ppart-sum + LN + alloc(bitonic, LDS-only) + write-sim + ww + Sp/Sw ----------------
__global__ __launch_bounds__(1024) void k_waddr(
    const float* __restrict__ ppart, const float* __restrict__ bp,
    const float* __restrict__ ln_g, const float* __restrict__ ln_b,
    const float* __restrict__ rwp, const float* __restrict__ wwp,
    const float* __restrict__ up, const float* __restrict__ mem,
    const float* __restrict__ prec,
    float* __restrict__ pvec, float* __restrict__ wwb, float* __restrict__ spsw)
{
  __shared__ float red[16];
  __shared__ float pvs[512];
  __shared__ float fg[4];
  __shared__ float kdir[64];
  __shared__ float scal[4];
  __shared__ unsigned long long sk[1024];
  __shared__ float wsums[16];
  __shared__ float af[1024];
  __shared__ float red8[16][8];
  int b = blockIdx.x, tid = threadIdx.x;
  int lane = tid & 63, wv = tid >> 6;
  // ---- LN ----
  float acc = 0.f, d = 0.f;
  if (tid < 512) {
    if (tid < Pp) {
      acc = bp[tid];
#pragma unroll
      for (int c=0;c<16;++c) acc += ppart[(size_t)c*16384 + b*512 + tid];
    }
    float s = acc;
    for (int o=32;o;o>>=1) s += __shfl_xor(s,o,64);
    if (lane==0) red[wv] = s;
  }
  __syncthreads();
  if (tid < 8){ float xx = red[tid]; for (int o=4;o;o>>=1) xx += __shfl_xor(xx,o,64); if (!tid) red[0]=xx; }
  __syncthreads();
  float mu = red[0] / (float)Pp;
  __syncthreads();
  if (tid < 512) {
    d = (tid < Pp) ? (acc - mu) : 0.f;
    float s2 = d*d;
    for (int o=32;o;o>>=1) s2 += __shfl_xor(s2,o,64);
    if (lane==0) red[wv] = s2;
  }
  __syncthreads();
  if (tid < 8){ float xx = red[tid]; for (int o=4;o;o>>=1) xx += __shfl_xor(xx,o,64); if (!tid) red[0]=xx; }
  __syncthreads();
  float var = red[0] / (float)Pp;
  if (tid < Pp) {
    float y = d / sqrtf(var + 1e-5f) * ln_g[tid] + ln_b[tid];
    pvec[b*512 + tid] = y;
    pvs[tid] = y;
  }
  __syncthreads();
  // ---- scalars from pvs ----
  if (tid < 4) fg[tid] = sigm(pvs[128+tid]);
  if (wv == 0) {
    float v = pvs[146 + lane];
    float s = v*v;
    for (int o=32;o;o>>=1) s += __shfl_xor(s,o,64);
    kdir[lane] = v / (sqrtf(s) + EPSN);
  }
  if (tid == 0) {
    scal[0] = sigm(pvs[132]);               // alloc gate
    scal[1] = sigm(pvs[133]);               // write gate
    scal[2] = 1.f + log1pf(expf(pvs[210])); // write strength
  }
  __syncthreads();
  // ---- usage + bitonic argsort + cumprod -> af (LDS only) ----
  float psi = 1.f;
#pragma unroll
  for (int r=0;r<4;r++) psi *= 1.f - fg[r]*rwp[b*(Rr*Nn) + r*Nn + tid];
  float u = up[b*Nn+tid], w = wwp[b*Nn+tid];
  float usage = (u + w - u*w)*psi;
  unsigned long long key = ((unsigned long long)__float_as_uint(usage) << 32) | (unsigned)tid;
  for (int k=2; k<=1024; k<<=1) {
    for (int j=k>>1; j>0; j>>=1) {
      bool lower = (tid & j) == 0;
      bool asc   = (tid & k) == 0;
      unsigned long long pk;
      if (j >= 64) {
        sk[tid] = key; __syncthreads();
        pk = sk[tid ^ j];
        __syncthreads();
      } else {
        pk = __shfl_xor(key, j, 64);
      }
      key = ((key < pk) == (lower == asc)) ? key : pk;
    }
  }
  float us = __uint_as_float((unsigned)(key >> 32));
  int order = (int)(key & 1023u);
  float v = us;
#pragma unroll
  for (int dd=1; dd<64; dd<<=1) {
    float p = __shfl_up(v, dd, 64);
    if (lane >= dd) v *= p;
  }
  if (lane == 63) wsums[wv] = v;
  __syncthreads();
  if (wv == 0) {
    float t = (lane < 16) ? wsums[lane] : 1.f;
#pragma unroll
    for (int dd=1; dd<16; dd<<=1) {
      float p = __shfl_up(t, dd, 64);
      if (lane >= dd) t *= p;
    }
    if (lane < 16) wsums[lane] = t;
  }
  __syncthreads();
  float prefix = (wv > 0) ? wsums[wv-1] : 1.f;
  af[order] = (1.f - us) * (v * prefix);
  // ---- write-key sim: thread = memory row ----
  float beta = scal[2];
  float dot = 0.f, s2 = 0.f;
  const float* mrow = mem + (size_t)(b*Nn + tid)*Mm;
#pragma unroll
  for (int j=0;j<16;j++){
    float4 mv = *reinterpret_cast<const float4*>(&mrow[j*4]);
    dot += mv.x*kdir[j*4] + mv.y*kdir[j*4+1] + mv.z*kdir[j*4+2] + mv.w*kdir[j*4+3];
    s2  += mv.x*mv.x + mv.y*mv.y + mv.z*mv.z + mv.w*mv.w;
  }
  float sim = beta * dot / (sqrtf(s2) + EPSN);
  // ---- block softmax over sim ----
  float m_ = sim;
  for (int o=32;o;o>>=1) m_ = fmaxf(m_, __shfl_xor(m_,o,64));
  if (lane==0) red[wv] = m_;
  __syncthreads();
  if (tid < 16){ float x = red[tid]; for (int o=8;o;o>>=1) x = fmaxf(x,__shfl_xor(x,o,64)); if (!tid) red[0]=x; }
  __syncthreads();
  float gmax = red[0];
  __syncthreads();
  float e = expf(sim - gmax);
  float ss = e;
  for (int o=32;o;o>>=1) ss += __shfl_xor(ss,o,64);
  if (lane==0) red[wv] = ss;
  __syncthreads();
  if (tid < 16){ float x = red[tid]; for (int o=8;o;o>>=1) x += __shfl_xor(x,o,64); if (!tid) red[0]=x; }
  __syncthreads();
  float wcn = e / red[0];
  float ag = scal[0], wg = scal[1];
  float wwn = wg * (ag*af[tid] + (1.f-ag)*wcn);
  wwb[b*Nn + tid] = wwn;
  // ---- Sp/Sw ----
  float p = prec[b*Nn + tid];
#pragma unroll
  for (int r=0;r<4;r++){
    float a = rwp[b*(Rr*Nn) + r*Nn + tid];
    float x1 = p*a, x2 = wwn*a;
    for (int o=32;o;o>>=1){ x1 += __shfl_xor(x1,o,64); x2 += __shfl_xor(x2,o,64); }
    if (lane==0){ red8[wv][r] = x1; red8[wv][4+r] = x2; }
  }
  __syncthreads();
  if (tid < 8) {
    float s = 0.f;
    for (int w2=0; w2<16; ++w2) s += red8[w2][tid];
    spsw[b*8 + tid] = s;
  }
}

// ---------------- fused: link scan 64-row tiles (x<32) + memupd (x>=32) ----------------
// R7-measured-good version: 2-way-max bank conflicts in all phases.
__global__ __launch_bounds__(256) void k_linksmem(
    const float* __restrict__ links, const float* __restrict__ rwp,
    const float* __restrict__ wwb, const float* __restrict__ pvec,
    const float* __restrict__ mem,
    float* __restrict__ S1p, float* __restrict__ S2p,
    float* __restrict__ T1p, float* __restrict__ T2p,
    float* __restrict__ diag, float* __restrict__ memn, float* __restrict__ simr)
{
  int b = blockIdx.y;
  int tid = threadIdx.x;
  if (blockIdx.x >= 32) {
    // ---- memupd role ----
    __shared__ float ev[64], wvv[64];
    __shared__ float kdir4[4][64];
    __shared__ float beta4[4];
    int stripe = blockIdx.x - 32;
    int wv = tid>>6, lane = tid&63;
    const float* pv = pvec + b*512;
    {
      float kv = pv[211 + wv*64 + lane];
      float s = kv*kv;
      for (int o=32;o;o>>=1) s += __shfl_xor(s,o,64);
      kdir4[wv][lane] = kv/(sqrtf(s)+EPSN);
      if (lane==0) beta4[wv] = 1.f + log1pf(expf(pv[467+wv]));
    }
    if (tid < 64) { wvv[tid] = pv[tid]; ev[tid] = sigm(pv[64+tid]); }
    __syncthreads();
    for (int t=0;t<16;++t){
      int n = stripe*64 + wv*16 + t;
      float wwn = wwb[b*Nn + n];
      float v = mem[(b*Nn+n)*Mm + lane];
      float nv = v*(1.f - wwn*ev[lane]) + wwn*wvv[lane];
      memn[(b*Nn+n)*Mm + lane] = nv;
      float s2 = nv*nv;
      float d0 = nv*kdir4[0][lane], d1 = nv*kdir4[1][lane];
      float d2 = nv*kdir4[2][lane], d3 = nv*kdir4[3][lane];
      for (int o=32;o;o>>=1){
        s2 += __shfl_xor(s2,o,64);
        d0 += __shfl_xor(d0,o,64); d1 += __shfl_xor(d1,o,64);
        d2 += __shfl_xor(d2,o,64); d3 += __shfl_xor(d3,o,64);
      }
      if (lane==0){
        float inv = 1.f/(sqrtf(s2)+EPSN);
        simr[(b*4+0)*Nn+n] = beta4[0]*d0*inv;
        simr[(b*4+1)*Nn+n] = beta4[1]*d1*inv;
        simr[(b*4+2)*Nn+n] = beta4[2]*d2*inv;
        simr[(b*4+3)*Nn+n] = beta4[3]*d3*inv;
      }
    }
    return;
  }
  // ---- links role: 64-row tile, pad-65 ----
  __shared__ float tile[64][65];
  __shared__ float ai[4][64], wai[4][64], aj[4][64], waj[4][64];
  int stripe = blockIdx.x >> 1, half = blockIdx.x & 1;
  int i0 = stripe*64, jbase = half*512;
  {
    int r = tid>>6, ii = tid&63;
    float a = rwp[b*(Rr*Nn) + r*Nn + i0+ii];
    ai[r][ii]  = a;
    wai[r][ii] = a * wwb[b*Nn + i0+ii];
  }
  float s1a[4]={0,0,0,0}, s2a[4]={0,0,0,0};
  const float* Lb = links + (size_t)b*Nn*Nn;
  const int lrow = tid>>4, c4 = tid&15;
  float4 pv4[4];
#pragma unroll
  for (int q=0;q<4;q++)
    pv4[q] = *reinterpret_cast<const float4*>(&Lb[(size_t)(i0+lrow+16*q)*Nn + jbase + c4*4]);
  const int dt = (half == (stripe>>3)) ? (stripe&7) : -1;
  for (int t=0; t<8; ++t) {
    int j0 = jbase + t*64;
    __syncthreads();
#pragma unroll
    for (int q=0;q<4;q++){
      int row = lrow + 16*q;
      float4 v = pv4[q];
      tile[row][c4*4+0]=v.x; tile[row][c4*4+1]=v.y;
      tile[row][c4*4+2]=v.z; tile[row][c4*4+3]=v.w;
    }
    {
      int r = tid>>6, jj = tid&63;
      float a = rwp[b*(Rr*Nn) + r*Nn + j0+jj];
      aj[r][jj]  = a;
      waj[r][jj] = a * wwb[b*Nn + j0+jj];
    }
    __syncthreads();
    if (t < 7) {
      int j0n = j0 + 64;
#pragma unroll
      for (int q=0;q<4;q++)
        pv4[q] = *reinterpret_cast<const float4*>(&Lb[(size_t)(i0+lrow+16*q)*Nn + j0n + c4*4]);
    }
    if (t == dt && tid < 64) diag[b*Nn + i0 + tid] = tile[tid][tid];
    // phase A: row partials
    {
      int ii = tid>>2, c = tid&3;
      float p1[4]={0,0,0,0}, p2[4]={0,0,0,0};
      for (int k=0;k<16;k++){
        int jj = c*16+k;
        float v = tile[ii][jj];
#pragma unroll
        for (int r=0;r<4;r++){ p1[r] += v*aj[r][jj]; p2[r] += v*waj[r][jj]; }
      }
#pragma unroll
      for (int r=0;r<4;r++){
        p1[r] += __shfl_xor(p1[r],1,64); p1[r] += __shfl_xor(p1[r],2,64);
        p2[r] += __shfl_xor(p2[r],1,64); p2[r] += __shfl_xor(p2[r],2,64);
      }
      if (c==0){
#pragma unroll
        for (int r=0;r<4;r++){ s1a[r] += p1[r]; s2a[r] += p2[r]; }
      }
    }
    // phase B: col partials (2-way: 16q%32 in {0,16} spreads lanes over 32 banks)
    {
      int jj = tid>>2, q = tid&3;
      float p1[4]={0,0,0,0}, p2[4]={0,0,0,0};
      for (int k=0;k<16;k++){
        int ii = q*16+k;
        float v = tile[ii][jj];
#pragma unroll
        for (int r=0;r<4;r++){ p1[r] += v*ai[r][ii]; p2[r] += v*wai[r][ii]; }
      }
#pragma unroll
      for (int r=0;r<4;r++){
        p1[r] += __shfl_xor(p1[r],1,64); p1[r] += __shfl_xor(p1[r],2,64);
        p2[r] += __shfl_xor(p2[r],1,64); p2[r] += __shfl_xor(p2[r],2,64);
      }
      if (q==0){
#pragma unroll
        for (int r=0;r<4;r++){
          size_t o = (size_t)(((b*4+r)*16 + stripe))*Nn + j0 + jj;
          T1p[o] = p1[r];
          T2p[o] = p2[r];
        }
      }
    }
  }
  if ((tid&3)==0){
    int ii = tid>>2;
#pragma unroll
    for (int r=0;r<4;r++){
      size_t o = (size_t)(((half*Bb + b)*4 + r))*Nn + i0 + ii;
      S1p[o] = s1a[r];
      S2p[o] = s2a[r];
    }
  }
}

// ---------------- fused: 4-way-parallel softmax+combine + reads GEMV + out bias ----------------
__global__ __launch_bounds__(1024) void k_rread(
    const float* __restrict__ pvec, const float* __restrict__ rwp,
    const float* __restrict__ prec, const float* __restrict__ wwb,
    const float* __restrict__ T1p, const float* __restrict__ T2p,
    const float* __restrict__ S1p, const float* __restrict__ S2p,
    const float* __restrict__ spsw, const float* __restrict__ diag,
    const float* __restrict__ simr, const float* __restrict__ memn,
    const float* __restrict__ bo, float* __restrict__ ocat, float* __restrict__ out)
{
  __shared__ float rwl[4][1024];
  __shared__ float redm[4][4], reds[4][4];
  __shared__ float rm3s[4][3];
  __shared__ float rp[16][4][64];
  int b = blockIdx.x, tid = threadIdx.x;
  int g = tid>>8, t256 = tid&255;           // group g handles r = g
  int wv4 = (tid>>6)&3, lane = tid&63;
  const float* pv = pvec + b*512;
  if (tid < 4) {
    float x0 = pv[134+tid*3], x1 = pv[134+tid*3+1], x2 = pv[134+tid*3+2];
    float mx = fmaxf(x0, fmaxf(x1,x2));
    float e0 = expf(x0-mx), e1 = expf(x1-mx), e2 = expf(x2-mx);
    float s = e0+e1+e2;
    rm3s[tid][0]=e0/s; rm3s[tid][1]=e1/s; rm3s[tid][2]=e2/s;
  }
  float v[4];
#pragma unroll
  for (int q=0;q<4;q++) v[q] = simr[(b*4+g)*Nn + t256 + 256*q];
  float m_ = fmaxf(fmaxf(v[0],v[1]), fmaxf(v[2],v[3]));
  for (int o=32;o;o>>=1) m_ = fmaxf(m_, __shfl_xor(m_,o,64));
  if (lane==0) redm[g][wv4] = m_;
  __syncthreads();
  float gmax = fmaxf(fmaxf(redm[g][0],redm[g][1]), fmaxf(redm[g][2],redm[g][3]));
  float e[4];
  float ss = 0.f;
#pragma unroll
  for (int q=0;q<4;q++){ e[q] = expf(v[q]-gmax); ss += e[q]; }
  for (int o=32;o;o>>=1) ss += __shfl_xor(ss,o,64);
  if (lane==0) reds[g][wv4] = ss;
  __syncthreads();
  float tot = reds[g][0]+reds[g][1]+reds[g][2]+reds[g][3];
  float Spr = spsw[b*8+g], Swr = spsw[b*8+4+g];
#pragma unroll
  for (int q=0;q<4;q++){
    int n = t256 + 256*q;
    float rc = e[q]/tot;
    float w_n = wwb[b*Nn + n];
    float p_n = prec[b*Nn + n];
    float Lii = diag[b*Nn + n];
    float a = rwp[b*(Rr*Nn)+g*Nn+n];
    float s1v = S1p[(size_t)((0*Bb+b)*4+g)*Nn + n] + S1p[(size_t)((1*Bb+b)*4+g)*Nn + n];
    float s2v = S2p[(size_t)((0*Bb+b)*4+g)*Nn + n] + S2p[(size_t)((1*Bb+b)*4+g)*Nn + n];
    float t1v = 0.f, t2v = 0.f;
#pragma unroll
    for (int st=0; st<16; ++st){
      size_t o = (size_t)((b*4+g)*16 + st)*Nn + n;
      t1v += T1p[o];
      t2v += T2p[o];
    }
    float fwd = (1.f-w_n)*(s1v - Lii*a) - (s2v - Lii*w_n*a) + w_n*(Spr - p_n*a);
    float bwd = (1.f-w_n)*(t1v - Lii*a) - (t2v - w_n*Lii*a) + p_n*(Swr - w_n*a);
    rwl[g][n] = rm3s[g][1]*rc + rm3s[g][0]*bwd + rm3s[g][2]*fwd;
  }
  __syncthreads();
  // reads = rw @ memn : wave wv covers n in [wv*64, wv*64+64)
  int wv = tid>>6;
  float a0=0.f, a1=0.f, a2=0.f, a3=0.f;
  for (int t=0;t<64;++t){
    int n = wv*64 + t;
    float mv = memn[(size_t)(b*Nn+n)*Mm + lane];
    a0 += rwl[0][n]*mv; a1 += rwl[1][n]*mv; a2 += rwl[2][n]*mv; a3 += rwl[3][n]*mv;
  }
  rp[wv][0][lane]=a0; rp[wv][1][lane]=a1; rp[wv][2][lane]=a2; rp[wv][3][lane]=a3;
  __syncthreads();
  if (tid < 256) {
    int r = tid>>6, m = tid&63;
    float s = 0.f;
#pragma unroll
    for (int w2=0;w2<16;++w2) s += rp[w2][r][m];
    ocat[b*1280 + 1024 + r*64 + m] = s;
    out[b*256 + tid] = bo[tid];
  }
}

// ---------------- output GEMM (atomic; out bias-inited by k_rread) ----------------
__global__ __launch_bounds__(256) void k_gout(
    const float* __restrict__ ocat, const float* __restrict__ Wo,
    float* __restrict__ out)
{
  __shared__ float lin[32][64];
  int tid = threadIdx.x;
  int col = blockIdx.x*64 + (tid & 63);
  int bg  = tid >> 6;
  int k0  = blockIdx.y*64;
#pragma unroll
  for (int q=0;q<8;q++){
    int idx = tid + 256*q;
    int bb = idx >> 6, kk = idx & 63;
    lin[bb][kk] = ocat[bb*1280 + k0 + kk];
  }
  __syncthreads();
  const float* Wr = Wo + (size_t)k0*256;
  float acc[8];
#pragma unroll
  for (int i=0;i<8;i++) acc[i]=0.f;
#pragma unroll 8
  for (int kk=0; kk<64; ++kk){
    float wv = Wr[(size_t)kk*256 + col];
#pragma unroll
    for (int bb=0; bb<8; ++bb) acc[bb] += wv * lin[bg*8+bb][kk];
  }
#pragma unroll
  for (int bb=0; bb<8; ++bb)
    atomicAdd(&out[(size_t)(bg*8+bb)*256 + col], acc[bb]);
}

extern "C" void kernel_launch(void* const* d_in, const int* in_sizes, int n_in,
                              void* d_out, int out_size, void* d_ws, size_t ws_size,
                              hipStream_t stream)
{
  (void)in_sizes; (void)n_in; (void)out_size; (void)ws_size;
  const float* X    = (const float*)d_in[0];
  const float* emb  = (const float*)d_in[1];
  const float* mem  = (const float*)d_in[2];
  const float* prvr = (const float*)d_in[3];
  const float* h0   = (const float*)d_in[4];
  const float* c0   = (const float*)d_in[5];
  const float* rwp  = (const float*)d_in[6];
  const float* wwp  = (const float*)d_in[7];
  const float* up   = (const float*)d_in[8];
  const float* prec = (const float*)d_in[9];
  const float* links= (const float*)d_in[10];
  const float* Wx   = (const float*)d_in[11];
  const float* Wh   = (const float*)d_in[12];
  const float* lb   = (const float*)d_in[13];
  const float* Wp   = (const float*)d_in[14];
  const float* bp   = (const float*)d_in[15];
  const float* lng  = (const float*)d_in[16];
  const float* lnb  = (const float*)d_in[17];
  const float* Wo   = (const float*)d_in[18];
  const float* bo   = (const float*)d_in[19];
  float* out = (float*)d_out;
  float* ws  = (float*)d_ws;

  float* memn  = ws;                       // 2097152
  float* T1p   = memn  + 2097152;          // 2097152 (32b x 4r x 16stripe x 1024)
  float* T2p   = T1p   + 2097152;          // 2097152
  float* S1p   = T2p   + 2097152;          // 262144  (2half x 32b x 4r x 1024)
  float* S2p   = S1p   + 262144;           // 262144
  float* gpart = S2p   + 262144;           // 1048576 (16c x 32b x 2048)
  float* ppart = gpart + 1048576;          // 262144  (16c x 32b x 512)
  float* pvec  = ppart + 262144;           // 16384   (stride 512, 471 used)
  float* wwb   = pvec  + 16384;            // 32768
  float* ocat  = wwb   + 32768;            // 40960   [h|emb|reads]
  float* spsw  = ocat  + 40960;            // 256
  float* simr  = spsw  + 256;              // 131072
  float* diag  = simr  + 131072;           // 32768
  float* hcat  = diag  + 32768;            // 32768   [h|emb]

  k_gates   <<<dim3(32,16), dim3(256),  0, stream>>>(X, prvr, h0, Wx, Wh, gpart);
  k_lstm_ep <<<dim3(64),    dim3(256),  0, stream>>>(gpart, lb, c0, emb, hcat, ocat);
  k_para    <<<dim3(8,16),  dim3(256),  0, stream>>>(hcat, Wp, ppart);
  k_waddr   <<<dim3(32),    dim3(1024), 0, stream>>>(ppart, bp, lng, lnb, rwp, wwp, up,
                                                     mem, prec, pvec, wwb, spsw);
  k_linksmem<<<dim3(48,32), dim3(256),  0, stream>>>(links, rwp, wwb, pvec, mem,
                                                     S1p, S2p, T1p, T2p, diag, memn, simr);
  k_rread   <<<dim3(32),    dim3(1024), 0, stream>>>(pvec, rwp, prec, wwb, T1p, T2p,
                                                     S1p, S2p, spsw, diag, simr, memn,
                                                     bo, ocat, out);
  k_gout    <<<dim3(4,20),  dim3(256),  0, stream>>>(ocat, Wo, out);
}